// Round 1
// baseline (168.699 us; speedup 1.0000x reference)
//
#include <hip/hip_runtime.h>

// ---------------------------------------------------------------------------
// Problem: per-batch dynamic conv stack + polynomial attention (f32).
//   feature (8,360) = mean(thumb,(2,3)) @ Wm + bm
//   conv_stack: residual + [3x conv3x3(SAME,leaky 0.2)] -> [5x conv1x1(leaky)]
//   attention:  out = y * (1 + prod_i(a*h + b*w + c*y + d)) per channel
// Outputs: x_out (8,3,512,512) then thumb_out (8,3,64,64), flat f32.
// ---------------------------------------------------------------------------

#define LEAKY(v) fmaxf((v), 0.2f * (v))

__global__ __launch_bounds__(256) void feat_kernel(
    const float* __restrict__ thumb, const float* __restrict__ Wm,
    const float* __restrict__ bm, float* __restrict__ feat)
{
    const int b = blockIdx.x;
    const int tid = threadIdx.x;
    __shared__ float red[256];
    __shared__ float smean[3];

    for (int c = 0; c < 3; ++c) {
        const float* p = thumb + (size_t)(b * 3 + c) * 4096;
        float s = 0.f;
        for (int i = tid; i < 4096; i += 256) s += p[i];
        red[tid] = s;
        __syncthreads();
        for (int off = 128; off > 0; off >>= 1) {
            if (tid < off) red[tid] += red[tid + off];
            __syncthreads();
        }
        if (tid == 0) smean[c] = red[0] * (1.f / 4096.f);
        __syncthreads();
    }
    const float m0 = smean[0], m1 = smean[1], m2 = smean[2];
    for (int f = tid; f < 360; f += 256) {
        feat[b * 360 + f] = m0 * Wm[f] + m1 * Wm[360 + f] + m2 * Wm[720 + f] + bm[f];
    }
}

// Tile: TH=32 x TW=64 output pixels per block, 256 threads, 8 px/thread.
// LDS: buf0 3x38x70 (input w/ halo 3, later reused as conv2 out 3x34x66),
//      buf1 3x36x68 (conv1 out). Total ~62.7 KB -> 2 blocks/CU.
__global__ __launch_bounds__(256) void conv_att_kernel(
    const float* __restrict__ x, const float* __restrict__ feat,
    float* __restrict__ out, int H, int W, int tilesW)
{
    constexpr int TH = 32, TW = 64, NP = 8;
    constexpr int H0 = TH + 6, W0 = TW + 6;  // 38 x 70
    constexpr int H1 = TH + 4, W1 = TW + 4;  // 36 x 68
    constexpr int H2 = TH + 2, W2 = TW + 2;  // 34 x 66

    __shared__ float sfeat[360];
    __shared__ float buf0[3 * H0 * W0];
    __shared__ float buf1[3 * H1 * W1];

    const int tid = threadIdx.x;
    const int b = blockIdx.y;
    const int tile = blockIdx.x;
    const int tr = (tile / tilesW) * TH;
    const int tc = (tile % tilesW) * TW;

    for (int i = tid; i < 360; i += 256) sfeat[i] = feat[b * 360 + i];

    // ---- load input tile (halo 3, zero-pad at image borders) ----
    const float* xb = x + (size_t)b * 3 * H * W;
    for (int i = tid; i < 3 * H0 * W0; i += 256) {
        int c = i / (H0 * W0);
        int rem = i - c * (H0 * W0);
        int r = rem / W0;
        int col = rem - r * W0;
        int gr = tr + r - 3, gc = tc + col - 3;
        float v = 0.f;
        if (gr >= 0 && gr < H && gc >= 0 && gc < W)
            v = xb[(size_t)c * H * W + (size_t)gr * W + gc];
        buf0[i] = v;
    }
    __syncthreads();

    // ---- stash residual (center of buf0; buf0 is overwritten by conv2) ----
    float res[3][NP];
#pragma unroll
    for (int k = 0; k < NP; ++k) {
        int p = k * 256 + tid;
        int r = p >> 6, cl = p & 63;
#pragma unroll
        for (int c = 0; c < 3; ++c)
            res[c][k] = buf0[c * (H0 * W0) + (r + 3) * W0 + (cl + 3)];
    }

    // ---- conv1: buf0 -> buf1 (region 36x68) ----
    {
        float wA[27], wB[27], wC[27];
#pragma unroll
        for (int j = 0; j < 27; ++j) {
            wA[j] = sfeat[0 + j];
            wB[j] = sfeat[27 + j];
            wC[j] = sfeat[54 + j];
        }
        const float bA = sfeat[81], bB = sfeat[82], bC = sfeat[83];
        for (int idx = tid; idx < H1 * W1; idx += 256) {
            int r = idx / W1;
            int cc = idx - r * W1;
            float a0 = bA, a1 = bB, a2 = bC;
#pragma unroll
            for (int i = 0; i < 3; ++i)
#pragma unroll
                for (int dy = 0; dy < 3; ++dy)
#pragma unroll
                    for (int dx = 0; dx < 3; ++dx) {
                        float v = buf0[i * (H0 * W0) + (r + dy) * W0 + (cc + dx)];
                        int j = i * 9 + dy * 3 + dx;
                        a0 = fmaf(v, wA[j], a0);
                        a1 = fmaf(v, wB[j], a1);
                        a2 = fmaf(v, wC[j], a2);
                    }
            buf1[0 * (H1 * W1) + idx] = LEAKY(a0);
            buf1[1 * (H1 * W1) + idx] = LEAKY(a1);
            buf1[2 * (H1 * W1) + idx] = LEAKY(a2);
        }
    }
    __syncthreads();

    // ---- conv2: buf1 -> buf0 (reused, region 34x66) ----
    {
        float wA[27], wB[27], wC[27];
#pragma unroll
        for (int j = 0; j < 27; ++j) {
            wA[j] = sfeat[84 + j];
            wB[j] = sfeat[111 + j];
            wC[j] = sfeat[138 + j];
        }
        const float bA = sfeat[165], bB = sfeat[166], bC = sfeat[167];
        for (int idx = tid; idx < H2 * W2; idx += 256) {
            int r = idx / W2;
            int cc = idx - r * W2;
            float a0 = bA, a1 = bB, a2 = bC;
#pragma unroll
            for (int i = 0; i < 3; ++i)
#pragma unroll
                for (int dy = 0; dy < 3; ++dy)
#pragma unroll
                    for (int dx = 0; dx < 3; ++dx) {
                        float v = buf1[i * (H1 * W1) + (r + dy) * W1 + (cc + dx)];
                        int j = i * 9 + dy * 3 + dx;
                        a0 = fmaf(v, wA[j], a0);
                        a1 = fmaf(v, wB[j], a1);
                        a2 = fmaf(v, wC[j], a2);
                    }
            buf0[0 * (H2 * W2) + idx] = LEAKY(a0);
            buf0[1 * (H2 * W2) + idx] = LEAKY(a1);
            buf0[2 * (H2 * W2) + idx] = LEAKY(a2);
        }
    }
    __syncthreads();

    // ---- conv3: buf0(as 3x34x66) -> registers y[3][NP] ----
    float y[3][NP];
    {
        float wA[27], wB[27], wC[27];
#pragma unroll
        for (int j = 0; j < 27; ++j) {
            wA[j] = sfeat[168 + j];
            wB[j] = sfeat[195 + j];
            wC[j] = sfeat[222 + j];
        }
        const float bA = sfeat[249], bB = sfeat[250], bC = sfeat[251];
#pragma unroll
        for (int k = 0; k < NP; ++k) {
            int p = k * 256 + tid;
            int r = p >> 6, cl = p & 63;
            float a0 = bA, a1 = bB, a2 = bC;
#pragma unroll
            for (int i = 0; i < 3; ++i)
#pragma unroll
                for (int dy = 0; dy < 3; ++dy)
#pragma unroll
                    for (int dx = 0; dx < 3; ++dx) {
                        float v = buf0[i * (H2 * W2) + (r + dy) * W2 + (cl + dx)];
                        int j = i * 9 + dy * 3 + dx;
                        a0 = fmaf(v, wA[j], a0);
                        a1 = fmaf(v, wB[j], a1);
                        a2 = fmaf(v, wC[j], a2);
                    }
            y[0][k] = LEAKY(a0);
            y[1][k] = LEAKY(a1);
            y[2][k] = LEAKY(a2);
        }
    }

    // ---- 5x conv1x1 chain in registers ----
#pragma unroll
    for (int l = 0; l < 5; ++l) {
        const int o = 252 + l * 12;
        const float w00 = sfeat[o + 0], w01 = sfeat[o + 1], w02 = sfeat[o + 2];
        const float w10 = sfeat[o + 3], w11 = sfeat[o + 4], w12 = sfeat[o + 5];
        const float w20 = sfeat[o + 6], w21 = sfeat[o + 7], w22 = sfeat[o + 8];
        const float c0 = sfeat[o + 9], c1 = sfeat[o + 10], c2 = sfeat[o + 11];
#pragma unroll
        for (int k = 0; k < NP; ++k) {
            float z0 = fmaf(y[0][k], w00, fmaf(y[1][k], w01, fmaf(y[2][k], w02, c0)));
            float z1 = fmaf(y[0][k], w10, fmaf(y[1][k], w11, fmaf(y[2][k], w12, c1)));
            float z2 = fmaf(y[0][k], w20, fmaf(y[1][k], w21, fmaf(y[2][k], w22, c2)));
            y[0][k] = LEAKY(z0);
            y[1][k] = LEAKY(z1);
            y[2][k] = LEAKY(z2);
        }
    }

    // ---- residual + attention + store ----
    const float invH = 1.f / (float)H;
    const float invW = 1.f / (float)W;
#pragma unroll
    for (int c = 0; c < 3; ++c) {
        const int o = 312 + c * 16;
        const float a0 = sfeat[o + 0], b0 = sfeat[o + 1], c0 = sfeat[o + 2], d0 = sfeat[o + 3];
        const float a1 = sfeat[o + 4], b1 = sfeat[o + 5], c1 = sfeat[o + 6], d1 = sfeat[o + 7];
        const float a2 = sfeat[o + 8], b2 = sfeat[o + 9], c2 = sfeat[o + 10], d2 = sfeat[o + 11];
        const float a3 = sfeat[o + 12], b3 = sfeat[o + 13], c3 = sfeat[o + 14], d3 = sfeat[o + 15];
#pragma unroll
        for (int k = 0; k < NP; ++k) {
            int p = k * 256 + tid;
            int r = p >> 6, cl = p & 63;
            float v = y[c][k] + res[c][k];
            float h = (float)(tr + r) * invH;
            float w = (float)(tc + cl) * invW;
            float att = fmaf(a0, h, fmaf(b0, w, fmaf(c0, v, d0)));
            att *= fmaf(a1, h, fmaf(b1, w, fmaf(c1, v, d1)));
            att *= fmaf(a2, h, fmaf(b2, w, fmaf(c2, v, d2)));
            att *= fmaf(a3, h, fmaf(b3, w, fmaf(c3, v, d3)));
            out[((size_t)(b * 3 + c) * H + (tr + r)) * W + (tc + cl)] = v * (1.f + att);
        }
    }
}

extern "C" void kernel_launch(void* const* d_in, const int* in_sizes, int n_in,
                              void* d_out, int out_size, void* d_ws, size_t ws_size,
                              hipStream_t stream) {
    const float* x = (const float*)d_in[0];       // (8,3,512,512)
    const float* thumb = (const float*)d_in[1];   // (8,3,64,64)
    const float* Wm = (const float*)d_in[2];      // (3,360)
    const float* bm = (const float*)d_in[3];      // (360,)
    float* out = (float*)d_out;
    float* feat = (float*)d_ws;                   // (8,360)

    feat_kernel<<<8, 256, 0, stream>>>(thumb, Wm, bm, feat);

    // x: 512x512 -> 16x8 = 128 tiles per batch
    conv_att_kernel<<<dim3(128, 8), 256, 0, stream>>>(x, feat, out, 512, 512, 8);
    // thumb: 64x64 -> 2x1 tiles per batch
    conv_att_kernel<<<dim3(2, 8), 256, 0, stream>>>(thumb, feat, out + (size_t)8 * 3 * 512 * 512,
                                                    64, 64, 1);
}

// Round 2
// 141.863 us; speedup vs baseline: 1.1892x; 1.1892x over previous
//
#include <hip/hip_runtime.h>

// ---------------------------------------------------------------------------
// Per-batch dynamic conv stack + polynomial attention (f32).
//   feature (8,360) = mean(thumb,(2,3)) @ Wm + bm
//   conv_stack: residual + [3x conv3x3(SAME,leaky 0.2)] -> [5x conv1x1(leaky)]
//   attention:  out = y * (1 + prod_i(a*h + b*w + c*y + d)) per channel
// Outputs: x_out (8,3,512,512) then thumb_out (8,3,64,64), flat f32.
//
// R2 design: tile 32 rows x 60 cols, 256 threads (4 waves). lane = column,
// wave = row-strip. Single 30KB LDS buffer reused across stages (compute into
// registers, sync, write back). Weights read via uniform global loads (SGPR).
// Sliding-window vertical strips: 33 LDS reads per 27 conv outputs per ich.
// ---------------------------------------------------------------------------

#define LEAKY(v) fmaxf((v), 0.2f * (v))

__global__ __launch_bounds__(256) void feat_kernel(
    const float* __restrict__ thumb, const float* __restrict__ Wm,
    const float* __restrict__ bm, float* __restrict__ feat)
{
    const int b = blockIdx.x;
    const int tid = threadIdx.x;
    __shared__ float red[256];
    __shared__ float smean[3];

    for (int c = 0; c < 3; ++c) {
        const float* p = thumb + (size_t)(b * 3 + c) * 4096;
        float s = 0.f;
        for (int i = tid; i < 4096; i += 256) s += p[i];
        red[tid] = s;
        __syncthreads();
        for (int off = 128; off > 0; off >>= 1) {
            if (tid < off) red[tid] += red[tid + off];
            __syncthreads();
        }
        if (tid == 0) smean[c] = red[0] * (1.f / 4096.f);
        __syncthreads();
    }
    const float m0 = smean[0], m1 = smean[1], m2 = smean[2];
    for (int f = tid; f < 360; f += 256) {
        feat[b * 360 + f] = m0 * Wm[f] + m1 * Wm[360 + f] + m2 * Wm[720 + f] + bm[f];
    }
}

// Sliding-window 3x3 conv over a vertical strip of R output rows, 1 column.
// sb: LDS stage base; fw: 84 uniform weights (global, SGPR-loaded);
// r0: first output row (tile-relative); c: output column (tile-relative).
// Stage layout: idx = ich*CHSTR + (row + RO)*STRIDE + (col + CO).
template<int R, int STRIDE, int CHSTR, int RO, int CO>
__device__ __forceinline__ void conv3x3_strip(
    const float* __restrict__ sb, const float* __restrict__ fw,
    int r0, int c, float* __restrict__ a0, float* __restrict__ a1,
    float* __restrict__ a2)
{
    const float b0 = fw[81], b1 = fw[82], b2 = fw[83];
#pragma unroll
    for (int j = 0; j < R; ++j) { a0[j] = b0; a1[j] = b1; a2[j] = b2; }

    for (int ich = 0; ich < 3; ++ich) {
        const float* wp = fw + ich * 9;      // uniform -> s_load
        float w0[9], w1[9], w2[9];
#pragma unroll
        for (int t = 0; t < 9; ++t) {
            w0[t] = wp[t]; w1[t] = wp[27 + t]; w2[t] = wp[54 + t];
        }
        const float* in = sb + ich * CHSTR + (c + CO - 1);
        float win[3][3];
#pragma unroll
        for (int t = 0; t < 2; ++t) {
            const float* rp = in + (r0 - 1 + t + RO) * STRIDE;
            win[t][0] = rp[0]; win[t][1] = rp[1]; win[t][2] = rp[2];
        }
#pragma unroll
        for (int j = 0; j < R; ++j) {
            const int tb = (j + 2) % 3;
            const float* rp = in + (r0 + j + 1 + RO) * STRIDE;
            win[tb][0] = rp[0]; win[tb][1] = rp[1]; win[tb][2] = rp[2];
#pragma unroll
            for (int dy = 0; dy < 3; ++dy) {
                const int s = (j + dy) % 3;
                const int tp = dy * 3;
#pragma unroll
                for (int dx = 0; dx < 3; ++dx) {
                    const float v = win[s][dx];
                    a0[j] = fmaf(v, w0[tp + dx], a0[j]);
                    a1[j] = fmaf(v, w1[tp + dx], a1[j]);
                    a2[j] = fmaf(v, w2[tp + dx], a2[j]);
                }
            }
        }
    }
}

// Stage geometry (tile output 32 rows x 60 cols):
//   stage0 (input):  rows -3..34 (38), cols -3..62 (66), stride 66, ch 2508
//   stage1 (conv1):  rows -2..33 (36), cols -2..61 (64), stride 64, ch 2304
//   stage2 (conv2):  rows -1..32 (34), cols -1..60 (62), stride 62, ch 2108
__global__ __launch_bounds__(256, 4) void conv_att_kernel(
    const float* __restrict__ x, const float* __restrict__ thumb,
    const float* __restrict__ feat, float* __restrict__ out)
{
    constexpr int S0 = 66, C0 = 2508;
    constexpr int S1 = 64, C1 = 2304;
    constexpr int S2 = 62, C2 = 2108;
    __shared__ float buf[3 * 38 * 66];   // 7524 floats = 30096 B

    int id = blockIdx.x;
    const float* src; float* dst; int H, W, tilesW, b, t;
    if (id < 1152) {                     // big image: 8 batches x (16x9) tiles
        b = id / 144; t = id - b * 144;
        H = 512; W = 512; tilesW = 9; src = x; dst = out;
    } else {                             // thumb: 8 batches x (2x2) tiles
        id -= 1152;
        b = id >> 2; t = id & 3;
        H = 64; W = 64; tilesW = 2; src = thumb;
        dst = out + (size_t)8 * 3 * 512 * 512;
    }
    const int trow = (t / tilesW) * 32;
    const int tcol = (t - (t / tilesW) * tilesW) * 60;
    const float* fb = feat + b * 360;    // uniform base -> scalar loads

    const int tid = threadIdx.x;
    const int l = tid & 63;              // lane = column
    const int w = tid >> 6;              // wave = row strip

    // ---- load stage0 (zero-pad outside the image) ----
    const float* sbg = src + (size_t)b * 3 * H * W;
    for (int i = tid; i < 3 * 38 * 66; i += 256) {
        int c = i / 2508;
        int rem = i - c * 2508;
        int r = rem / 66;
        int col = rem - r * 66;
        int gr = trow + r - 3, gc = tcol + col - 3;
        float v = 0.f;
        if ((unsigned)gr < (unsigned)H && (unsigned)gc < (unsigned)W)
            v = sbg[(size_t)c * H * W + gr * W + gc];
        buf[i] = v;
    }
    __syncthreads();

    // ---- residual stash (stage0 center, before buffer reuse) ----
    float res0[8], res1[8], res2[8];
#pragma unroll
    for (int j = 0; j < 8; ++j) {
        const int idx = (8 * w + j + 3) * S0 + (l + 3);
        res0[j] = buf[idx]; res1[j] = buf[C0 + idx]; res2[j] = buf[2 * C0 + idx];
    }

    float a0[9], a1[9], a2[9];

    // ---- conv1: stage0 -> regs -> stage1 (rows 9w-2..9w+6, col l-2) ----
    conv3x3_strip<9, S0, C0, 3, 3>(buf, fb, 9 * w - 2, l - 2, a0, a1, a2);
    __syncthreads();
#pragma unroll
    for (int j = 0; j < 9; ++j) {
        const int idx = (9 * w + j) * S1 + l;    // (r+2)*S1 + (c+2)
        buf[idx] = LEAKY(a0[j]);
        buf[C1 + idx] = LEAKY(a1[j]);
        buf[2 * C1 + idx] = LEAKY(a2[j]);
    }
    __syncthreads();

    // ---- conv2: stage1 -> regs -> stage2 (rows 9w-1..9w+7, col l-1) ----
    conv3x3_strip<9, S1, C1, 2, 2>(buf, fb + 84, 9 * w - 1, l - 1, a0, a1, a2);
    __syncthreads();
#pragma unroll
    for (int j = 0; j < 9; ++j) {
        const int r = 9 * w - 1 + j;
        if (r <= 32 && l <= 61) {
            const int idx = (r + 1) * S2 + l;    // (r+1)*S2 + (c+1), c=l-1
            buf[idx] = LEAKY(a0[j]);
            buf[C2 + idx] = LEAKY(a1[j]);
            buf[2 * C2 + idx] = LEAKY(a2[j]);
        }
    }
    __syncthreads();

    // ---- conv3: stage2 -> regs (rows 8w..8w+7, col l) ----
    float y0[8], y1[8], y2[8];
    conv3x3_strip<8, S2, C2, 1, 1>(buf, fb + 168, 8 * w, l, y0, y1, y2);
#pragma unroll
    for (int j = 0; j < 8; ++j) {
        y0[j] = LEAKY(y0[j]); y1[j] = LEAKY(y1[j]); y2[j] = LEAKY(y2[j]);
    }

    // ---- 5x conv1x1 chain in registers ----
#pragma unroll
    for (int lay = 0; lay < 5; ++lay) {
        const float* fw = fb + 252 + lay * 12;
        const float w00 = fw[0], w01 = fw[1], w02 = fw[2];
        const float w10 = fw[3], w11 = fw[4], w12 = fw[5];
        const float w20 = fw[6], w21 = fw[7], w22 = fw[8];
        const float c0 = fw[9], c1 = fw[10], c2 = fw[11];
#pragma unroll
        for (int j = 0; j < 8; ++j) {
            const float z0 = fmaf(y0[j], w00, fmaf(y1[j], w01, fmaf(y2[j], w02, c0)));
            const float z1 = fmaf(y0[j], w10, fmaf(y1[j], w11, fmaf(y2[j], w12, c1)));
            const float z2 = fmaf(y0[j], w20, fmaf(y1[j], w21, fmaf(y2[j], w22, c2)));
            y0[j] = LEAKY(z0); y1[j] = LEAKY(z1); y2[j] = LEAKY(z2);
        }
    }

    // ---- residual + attention + store ----
    const int gc = tcol + l;
    if (l < 60 && gc < W) {
        const float invH = 1.f / (float)H;
        const float invW = 1.f / (float)W;
        const float wc = (float)gc * invW;
#pragma unroll
        for (int ch = 0; ch < 3; ++ch) {
            const float* fp = fb + 312 + ch * 16;
            const float pa0 = fp[0], pb0 = fp[1], pc0 = fp[2], pd0 = fp[3];
            const float pa1 = fp[4], pb1 = fp[5], pc1 = fp[6], pd1 = fp[7];
            const float pa2 = fp[8], pb2 = fp[9], pc2 = fp[10], pd2 = fp[11];
            const float pa3 = fp[12], pb3 = fp[13], pc3 = fp[14], pd3 = fp[15];
            const float* yv = (ch == 0) ? y0 : (ch == 1) ? y1 : y2;
            const float* rv = (ch == 0) ? res0 : (ch == 1) ? res1 : res2;
#pragma unroll
            for (int j = 0; j < 8; ++j) {
                const int gr = trow + 8 * w + j;
                const float v = yv[j] + rv[j];
                const float h = (float)gr * invH;
                float att = fmaf(pa0, h, fmaf(pb0, wc, fmaf(pc0, v, pd0)));
                att *= fmaf(pa1, h, fmaf(pb1, wc, fmaf(pc1, v, pd1)));
                att *= fmaf(pa2, h, fmaf(pb2, wc, fmaf(pc2, v, pd2)));
                att *= fmaf(pa3, h, fmaf(pb3, wc, fmaf(pc3, v, pd3)));
                dst[((size_t)(b * 3 + ch) * H + gr) * W + gc] = v * (1.f + att);
            }
        }
    }
}

extern "C" void kernel_launch(void* const* d_in, const int* in_sizes, int n_in,
                              void* d_out, int out_size, void* d_ws, size_t ws_size,
                              hipStream_t stream) {
    const float* x = (const float*)d_in[0];       // (8,3,512,512)
    const float* thumb = (const float*)d_in[1];   // (8,3,64,64)
    const float* Wm = (const float*)d_in[2];      // (3,360)
    const float* bm = (const float*)d_in[3];      // (360,)
    float* out = (float*)d_out;
    float* feat = (float*)d_ws;                   // (8,360)

    feat_kernel<<<8, 256, 0, stream>>>(thumb, Wm, bm, feat);
    // 1152 big-image blocks + 32 thumb blocks in one launch
    conv_att_kernel<<<1184, 256, 0, stream>>>(x, thumb, feat, out);
}

// Round 3
// 126.990 us; speedup vs baseline: 1.3284x; 1.1171x over previous
//
#include <hip/hip_runtime.h>

// ---------------------------------------------------------------------------
// Per-batch dynamic conv stack + polynomial attention (f32).
//   feature (8,360) = mean(thumb,(2,3)) @ Wm + bm
//   conv_stack: residual + [3x conv3x3(SAME,leaky 0.2)] -> [5x conv1x1(leaky)]
//   attention:  out = y * (1 + prod_i(a*h + b*w + c*y + d)) per channel
// Outputs: x_out (8,3,512,512) then thumb_out (8,3,64,64), flat f32.
//
// R3: tile 32 rows x 64 cols. Single LDS buffer (3 ch x 38 rows x 72 cols,
// col m = col+4, row mr = row+3), in-place stage reuse with 5 barriers.
// Conv units = (row-strip R x 4 cols x 3 och); windows read as 3x ds_read_b128
// per (row,ich) (conflict-free), weights via uniform s_loads, outputs float4.
// ---------------------------------------------------------------------------

#define LEAKY(v) fmaxf((v), 0.2f * (v))

constexpr int STRD = 72;            // dwords per buffered row
constexpr int CHS  = 38 * 72;       // 2736 dwords per channel slab
constexpr int BUFSZ = 3 * CHS + 16; // + pad for right-edge overread

__global__ __launch_bounds__(256) void means_kernel(
    const float* __restrict__ thumb, float* __restrict__ ws)
{
    const int bc = blockIdx.x;               // b*3+c, 24 blocks
    const int tid = threadIdx.x;
    const float4* p = (const float4*)(thumb + (size_t)bc * 4096);
    float s = 0.f;
#pragma unroll
    for (int k = 0; k < 4; ++k) {
        float4 v = p[tid + k * 256];
        s += v.x + v.y + v.z + v.w;
    }
    __shared__ float red[256];
    red[tid] = s;
    __syncthreads();
    for (int off = 128; off > 0; off >>= 1) {
        if (tid < off) red[tid] += red[tid + off];
        __syncthreads();
    }
    if (tid == 0) ws[bc] = red[0] * (1.f / 4096.f);
}

__global__ __launch_bounds__(384) void fmm_kernel(
    const float* __restrict__ Wm, const float* __restrict__ bm,
    const float* __restrict__ ws, float* __restrict__ feat)
{
    const int b = blockIdx.x;                // 8 blocks
    const int f = threadIdx.x;
    if (f < 360) {
        const float m0 = ws[b * 3 + 0], m1 = ws[b * 3 + 1], m2 = ws[b * 3 + 2];
        feat[b * 360 + f] =
            fmaf(m0, Wm[f], fmaf(m1, Wm[360 + f], fmaf(m2, Wm[720 + f], bm[f])));
    }
}

// 3x3 conv over a strip of R output rows x 4 cols (gx..gx+3), all 3 och.
// fw: 84 uniform weights; r0: first output row; gx: first col (multiple of 4,
// may be -4). CLAMPROW: clamp bottom row reads (garbage feeds discarded rows).
template<int R, bool CLAMPROW>
__device__ __forceinline__ void conv_rows(
    const float* __restrict__ buf, const float* __restrict__ fw,
    int r0, int gx, float4 acc[][3])
{
    const float b0 = fw[81], b1 = fw[82], b2 = fw[83];
#pragma unroll
    for (int j = 0; j < R; ++j) {
        acc[j][0] = make_float4(b0, b0, b0, b0);
        acc[j][1] = make_float4(b1, b1, b1, b1);
        acc[j][2] = make_float4(b2, b2, b2, b2);
    }
    const int gA = (gx < 0) ? 0 : gx;   // left-edge clamp: garbage only feeds
                                        // discarded cols <= -3
#pragma unroll
    for (int ich = 0; ich < 3; ++ich) {
#pragma unroll
        for (int ri = 0; ri < R + 2; ++ri) {
            int mr = r0 - 1 + ri + 3;
            if (CLAMPROW) mr = (mr > 37) ? 37 : mr;
            const int idx = ich * CHS + mr * STRD;
            const float4 A = *(const float4*)&buf[idx + gA];        // cols gx-4..gx-1
            const float4 B = *(const float4*)&buf[idx + gx + 4];    // cols gx..gx+3
            const float4 C = *(const float4*)&buf[idx + gx + 8];    // cols gx+4..gx+7
#pragma unroll
            for (int j = 0; j < R; ++j) {
                const int dy = ri - j;
                if (dy < 0 || dy > 2) continue;
#pragma unroll
                for (int oc = 0; oc < 3; ++oc) {
                    const float w0 = fw[oc * 27 + ich * 9 + dy * 3 + 0];
                    const float w1 = fw[oc * 27 + ich * 9 + dy * 3 + 1];
                    const float w2 = fw[oc * 27 + ich * 9 + dy * 3 + 2];
                    float4& a = acc[j][oc];
                    a.x = fmaf(A.w, w0, fmaf(B.x, w1, fmaf(B.y, w2, a.x)));
                    a.y = fmaf(B.x, w0, fmaf(B.y, w1, fmaf(B.z, w2, a.y)));
                    a.z = fmaf(B.y, w0, fmaf(B.z, w1, fmaf(B.w, w2, a.z)));
                    a.w = fmaf(B.z, w0, fmaf(B.w, w1, fmaf(C.x, w2, a.w)));
                }
            }
        }
    }
}

__global__ __launch_bounds__(256, 4) void conv_att_kernel(
    const float* __restrict__ x, const float* __restrict__ thumb,
    const float* __restrict__ feat, float* __restrict__ out)
{
    __shared__ float buf[BUFSZ];

    int id = blockIdx.x;
    const float* src; float* dst; int H, W, b, trow, tcol;
    if (id < 1024) {                 // big: 8 batches x (16 row x 8 col) tiles
        b = id >> 7; const int t = id & 127;
        H = 512; W = 512; trow = (t >> 3) * 32; tcol = (t & 7) * 64;
        src = x; dst = out;
    } else {                         // thumb: 8 batches x 2 row tiles
        const int i2 = id - 1024;
        b = i2 >> 1; trow = (i2 & 1) * 32; tcol = 0;
        H = 64; W = 64; src = thumb;
        dst = out + (size_t)8 * 3 * 512 * 512;
    }
    const float* fb = feat + b * 360;    // uniform -> scalar loads
    const int tid = threadIdx.x;

    // ---- stage0 load: 2052 float4 slots (3ch x 38 rows x 18 quads) ----
    const float* sbg = src + (size_t)b * 3 * H * W;
    for (int q = tid; q < 2052; q += 256) {
        const int c = q / 684;                 // 684 = 38*18
        const int rem = q - c * 684;
        const int mr = rem / 18;
        const int mq = rem - mr * 18;
        const int gr = trow + mr - 3;
        const int gc0 = tcol + 4 * mq - 4;
        const bool rok = (unsigned)gr < (unsigned)H;
        const float* gp = sbg + (size_t)c * H * W + (size_t)(rok ? gr : 0) * W;
        float4 v;
        v.x = (rok && (unsigned)(gc0 + 0) < (unsigned)W) ? gp[gc0 + 0] : 0.f;
        v.y = (rok && (unsigned)(gc0 + 1) < (unsigned)W) ? gp[gc0 + 1] : 0.f;
        v.z = (rok && (unsigned)(gc0 + 2) < (unsigned)W) ? gp[gc0 + 2] : 0.f;
        v.w = (rok && (unsigned)(gc0 + 3) < (unsigned)W) ? gp[gc0 + 3] : 0.f;
        *(float4*)&buf[c * CHS + mr * STRD + 4 * mq] = v;
    }
    __syncthreads();

    // conv3/output mapping (also used for residual): 16 strips x 16 groups
    const int s3 = tid >> 4;
    const int gx3 = 4 * (tid & 15);

    // ---- phase 1: residual stash + conv1 compute (reads stage0) ----
    float4 res[2][3];
#pragma unroll
    for (int j = 0; j < 2; ++j)
#pragma unroll
        for (int c = 0; c < 3; ++c)
            res[j][c] = *(const float4*)&buf[c * CHS + (2 * s3 + j + 3) * STRD + gx3 + 4];

    // conv1: 12 strips (R=3) x 18 groups = 216 units; rows -2..33, cols -4..67
    const bool act12 = tid < 216;
    const int s12 = tid / 18;
    const int g12 = tid - s12 * 18;
    const int gx12 = 4 * g12 - 4;
    float4 acc[3][3];
    if (act12) conv_rows<3, false>(buf, fb, 3 * s12 - 2, gx12, acc);
    __syncthreads();

    if (act12) {
        const int r0 = 3 * s12 - 2;
#pragma unroll
        for (int j = 0; j < 3; ++j)
#pragma unroll
            for (int oc = 0; oc < 3; ++oc) {
                float4 v = acc[j][oc];
                v.x = LEAKY(v.x); v.y = LEAKY(v.y); v.z = LEAKY(v.z); v.w = LEAKY(v.w);
                *(float4*)&buf[oc * CHS + (r0 + j + 3) * STRD + gx12 + 4] = v;
            }
    }
    __syncthreads();

    // ---- conv2: rows -1..32 (strips r0=3s-1, bottom rows clipped) ----
    if (act12) conv_rows<3, true>(buf, fb + 84, 3 * s12 - 1, gx12, acc);
    __syncthreads();

    if (act12) {
        const int r0 = 3 * s12 - 1;
#pragma unroll
        for (int j = 0; j < 3; ++j) {
            if (r0 + j > 32) continue;
#pragma unroll
            for (int oc = 0; oc < 3; ++oc) {
                float4 v = acc[j][oc];
                v.x = LEAKY(v.x); v.y = LEAKY(v.y); v.z = LEAKY(v.z); v.w = LEAKY(v.w);
                *(float4*)&buf[oc * CHS + (r0 + j + 3) * STRD + gx12 + 4] = v;
            }
        }
    }
    __syncthreads();

    // ---- conv3: rows 0..31, 16 strips (R=2) x 16 groups = 256 units ----
    float4 y[2][3];
    conv_rows<2, false>(buf, fb + 168, 2 * s3, gx3, y);
#pragma unroll
    for (int j = 0; j < 2; ++j)
#pragma unroll
        for (int oc = 0; oc < 3; ++oc) {
            y[j][oc].x = LEAKY(y[j][oc].x); y[j][oc].y = LEAKY(y[j][oc].y);
            y[j][oc].z = LEAKY(y[j][oc].z); y[j][oc].w = LEAKY(y[j][oc].w);
        }

    // ---- 5x conv1x1 chain in registers ----
#pragma unroll
    for (int lay = 0; lay < 5; ++lay) {
        const float* fw = fb + 252 + lay * 12;
        const float w00 = fw[0], w01 = fw[1], w02 = fw[2];
        const float w10 = fw[3], w11 = fw[4], w12 = fw[5];
        const float w20 = fw[6], w21 = fw[7], w22 = fw[8];
        const float c0 = fw[9], c1 = fw[10], c2 = fw[11];
#pragma unroll
        for (int j = 0; j < 2; ++j) {
            float4 z0, z1, z2;
            z0.x = fmaf(y[j][0].x, w00, fmaf(y[j][1].x, w01, fmaf(y[j][2].x, w02, c0)));
            z0.y = fmaf(y[j][0].y, w00, fmaf(y[j][1].y, w01, fmaf(y[j][2].y, w02, c0)));
            z0.z = fmaf(y[j][0].z, w00, fmaf(y[j][1].z, w01, fmaf(y[j][2].z, w02, c0)));
            z0.w = fmaf(y[j][0].w, w00, fmaf(y[j][1].w, w01, fmaf(y[j][2].w, w02, c0)));
            z1.x = fmaf(y[j][0].x, w10, fmaf(y[j][1].x, w11, fmaf(y[j][2].x, w12, c1)));
            z1.y = fmaf(y[j][0].y, w10, fmaf(y[j][1].y, w11, fmaf(y[j][2].y, w12, c1)));
            z1.z = fmaf(y[j][0].z, w10, fmaf(y[j][1].z, w11, fmaf(y[j][2].z, w12, c1)));
            z1.w = fmaf(y[j][0].w, w10, fmaf(y[j][1].w, w11, fmaf(y[j][2].w, w12, c1)));
            z2.x = fmaf(y[j][0].x, w20, fmaf(y[j][1].x, w21, fmaf(y[j][2].x, w22, c2)));
            z2.y = fmaf(y[j][0].y, w20, fmaf(y[j][1].y, w21, fmaf(y[j][2].y, w22, c2)));
            z2.z = fmaf(y[j][0].z, w20, fmaf(y[j][1].z, w21, fmaf(y[j][2].z, w22, c2)));
            z2.w = fmaf(y[j][0].w, w20, fmaf(y[j][1].w, w21, fmaf(y[j][2].w, w22, c2)));
            y[j][0].x = LEAKY(z0.x); y[j][0].y = LEAKY(z0.y); y[j][0].z = LEAKY(z0.z); y[j][0].w = LEAKY(z0.w);
            y[j][1].x = LEAKY(z1.x); y[j][1].y = LEAKY(z1.y); y[j][1].z = LEAKY(z1.z); y[j][1].w = LEAKY(z1.w);
            y[j][2].x = LEAKY(z2.x); y[j][2].y = LEAKY(z2.y); y[j][2].z = LEAKY(z2.z); y[j][2].w = LEAKY(z2.w);
        }
    }

    // ---- residual + attention + float4 store ----
    const float invH = 1.f / (float)H;
    const float invW = 1.f / (float)W;
    const float wbase = (float)(tcol + gx3) * invW;
    const float4 wv = make_float4(wbase, wbase + invW, wbase + 2.f * invW, wbase + 3.f * invW);
#pragma unroll
    for (int ch = 0; ch < 3; ++ch) {
        const float* fp = fb + 312 + ch * 16;
        const float pa0 = fp[0], pb0 = fp[1], pc0 = fp[2], pd0 = fp[3];
        const float pa1 = fp[4], pb1 = fp[5], pc1 = fp[6], pd1 = fp[7];
        const float pa2 = fp[8], pb2 = fp[9], pc2 = fp[10], pd2 = fp[11];
        const float pa3 = fp[12], pb3 = fp[13], pc3 = fp[14], pd3 = fp[15];
#pragma unroll
        for (int j = 0; j < 2; ++j) {
            const int gr = trow + 2 * s3 + j;
            const float h = (float)gr * invH;
            float4 v;
            v.x = y[j][ch].x + res[j][ch].x;
            v.y = y[j][ch].y + res[j][ch].y;
            v.z = y[j][ch].z + res[j][ch].z;
            v.w = y[j][ch].w + res[j][ch].w;
            const float t0 = fmaf(pa0, h, pd0), t1 = fmaf(pa1, h, pd1);
            const float t2 = fmaf(pa2, h, pd2), t3 = fmaf(pa3, h, pd3);
            float4 o;
            {
                float a0 = fmaf(pb0, wv.x, fmaf(pc0, v.x, t0));
                a0 *= fmaf(pb1, wv.x, fmaf(pc1, v.x, t1));
                a0 *= fmaf(pb2, wv.x, fmaf(pc2, v.x, t2));
                a0 *= fmaf(pb3, wv.x, fmaf(pc3, v.x, t3));
                o.x = v.x * (1.f + a0);
                float a1 = fmaf(pb0, wv.y, fmaf(pc0, v.y, t0));
                a1 *= fmaf(pb1, wv.y, fmaf(pc1, v.y, t1));
                a1 *= fmaf(pb2, wv.y, fmaf(pc2, v.y, t2));
                a1 *= fmaf(pb3, wv.y, fmaf(pc3, v.y, t3));
                o.y = v.y * (1.f + a1);
                float a2 = fmaf(pb0, wv.z, fmaf(pc0, v.z, t0));
                a2 *= fmaf(pb1, wv.z, fmaf(pc1, v.z, t1));
                a2 *= fmaf(pb2, wv.z, fmaf(pc2, v.z, t2));
                a2 *= fmaf(pb3, wv.z, fmaf(pc3, v.z, t3));
                o.z = v.z * (1.f + a2);
                float a3 = fmaf(pb0, wv.w, fmaf(pc0, v.w, t0));
                a3 *= fmaf(pb1, wv.w, fmaf(pc1, v.w, t1));
                a3 *= fmaf(pb2, wv.w, fmaf(pc2, v.w, t2));
                a3 *= fmaf(pb3, wv.w, fmaf(pc3, v.w, t3));
                o.w = v.w * (1.f + a3);
            }
            *(float4*)&dst[((size_t)(b * 3 + ch) * H + gr) * W + tcol + gx3] = o;
        }
    }
}

extern "C" void kernel_launch(void* const* d_in, const int* in_sizes, int n_in,
                              void* d_out, int out_size, void* d_ws, size_t ws_size,
                              hipStream_t stream) {
    const float* x = (const float*)d_in[0];       // (8,3,512,512)
    const float* thumb = (const float*)d_in[1];   // (8,3,64,64)
    const float* Wm = (const float*)d_in[2];      // (3,360)
    const float* bm = (const float*)d_in[3];      // (360,)
    float* out = (float*)d_out;
    float* means = (float*)d_ws;                  // 24 floats
    float* feat = (float*)d_ws + 64;              // (8,360)

    means_kernel<<<24, 256, 0, stream>>>(thumb, means);
    fmm_kernel<<<8, 384, 0, stream>>>(Wm, bm, means, feat);
    conv_att_kernel<<<1040, 256, 0, stream>>>(x, thumb, feat, out);
}

// Round 4
// 124.786 us; speedup vs baseline: 1.3519x; 1.0177x over previous
//
#include <hip/hip_runtime.h>

// ---------------------------------------------------------------------------
// Per-batch dynamic conv stack + polynomial attention (f32).
//   feature (8,360) = mean(thumb,(2,3)) @ Wm + bm
//   conv_stack: residual + [3x conv3x3(SAME,leaky 0.2)] -> [5x conv1x1(leaky)]
//   attention:  out = y * (1 + prod_i(a*h + b*w + c*y + d)) per channel
// Outputs: x_out (8,3,512,512) then thumb_out (8,3,64,64), flat f32.
//
// R4: same structure as R3 (tile 32x64, single in-place LDS buffer, float4
// conv units, uniform s_load weights) with the spill fix:
//   * __launch_bounds__(256, 2): LDS (33KB) caps occupancy at 4 blocks/CU,
//     so capping regs at 128 (R3's (256,4) made the allocator target 64 regs
//     -> scratch spills -> +37MB HBM writes). Give the allocator room.
//   * residual stash moved after conv1's reads (shorter liveness).
//   * interior stage0 quads load as one float4 (4 predicated scalars only
//     at image borders).
// ---------------------------------------------------------------------------

#define LEAKY(v) fmaxf((v), 0.2f * (v))

constexpr int STRD = 72;            // dwords per buffered row
constexpr int CHS  = 38 * 72;       // 2736 dwords per channel slab
constexpr int BUFSZ = 3 * CHS + 16; // + pad for right-edge overread

__global__ __launch_bounds__(256) void means_kernel(
    const float* __restrict__ thumb, float* __restrict__ ws)
{
    const int bc = blockIdx.x;               // b*3+c, 24 blocks
    const int tid = threadIdx.x;
    const float4* p = (const float4*)(thumb + (size_t)bc * 4096);
    float s = 0.f;
#pragma unroll
    for (int k = 0; k < 4; ++k) {
        float4 v = p[tid + k * 256];
        s += v.x + v.y + v.z + v.w;
    }
    __shared__ float red[256];
    red[tid] = s;
    __syncthreads();
    for (int off = 128; off > 0; off >>= 1) {
        if (tid < off) red[tid] += red[tid + off];
        __syncthreads();
    }
    if (tid == 0) ws[bc] = red[0] * (1.f / 4096.f);
}

__global__ __launch_bounds__(384) void fmm_kernel(
    const float* __restrict__ Wm, const float* __restrict__ bm,
    const float* __restrict__ ws, float* __restrict__ feat)
{
    const int b = blockIdx.x;                // 8 blocks
    const int f = threadIdx.x;
    if (f < 360) {
        const float m0 = ws[b * 3 + 0], m1 = ws[b * 3 + 1], m2 = ws[b * 3 + 2];
        feat[b * 360 + f] =
            fmaf(m0, Wm[f], fmaf(m1, Wm[360 + f], fmaf(m2, Wm[720 + f], bm[f])));
    }
}

// 3x3 conv over a strip of R output rows x 4 cols (gx..gx+3), all 3 och.
// fw: 84 uniform weights; r0: first output row; gx: first col (multiple of 4,
// may be -4). CLAMPROW: clamp bottom row reads (garbage feeds discarded rows).
template<int R, bool CLAMPROW>
__device__ __forceinline__ void conv_rows(
    const float* __restrict__ buf, const float* __restrict__ fw,
    int r0, int gx, float4 acc[][3])
{
    const float b0 = fw[81], b1 = fw[82], b2 = fw[83];
#pragma unroll
    for (int j = 0; j < R; ++j) {
        acc[j][0] = make_float4(b0, b0, b0, b0);
        acc[j][1] = make_float4(b1, b1, b1, b1);
        acc[j][2] = make_float4(b2, b2, b2, b2);
    }
    const int gA = (gx < 0) ? 0 : gx;   // left-edge clamp: garbage only feeds
                                        // discarded cols <= -3
#pragma unroll
    for (int ich = 0; ich < 3; ++ich) {
#pragma unroll
        for (int ri = 0; ri < R + 2; ++ri) {
            int mr = r0 - 1 + ri + 3;
            if (CLAMPROW) mr = (mr > 37) ? 37 : mr;
            const int idx = ich * CHS + mr * STRD;
            const float4 A = *(const float4*)&buf[idx + gA];        // cols gx-4..gx-1
            const float4 B = *(const float4*)&buf[idx + gx + 4];    // cols gx..gx+3
            const float4 C = *(const float4*)&buf[idx + gx + 8];    // cols gx+4..gx+7
#pragma unroll
            for (int j = 0; j < R; ++j) {
                const int dy = ri - j;
                if (dy < 0 || dy > 2) continue;
#pragma unroll
                for (int oc = 0; oc < 3; ++oc) {
                    const float w0 = fw[oc * 27 + ich * 9 + dy * 3 + 0];
                    const float w1 = fw[oc * 27 + ich * 9 + dy * 3 + 1];
                    const float w2 = fw[oc * 27 + ich * 9 + dy * 3 + 2];
                    float4& a = acc[j][oc];
                    a.x = fmaf(A.w, w0, fmaf(B.x, w1, fmaf(B.y, w2, a.x)));
                    a.y = fmaf(B.x, w0, fmaf(B.y, w1, fmaf(B.z, w2, a.y)));
                    a.z = fmaf(B.y, w0, fmaf(B.z, w1, fmaf(B.w, w2, a.z)));
                    a.w = fmaf(B.z, w0, fmaf(B.w, w1, fmaf(C.x, w2, a.w)));
                }
            }
        }
    }
}

__global__ __launch_bounds__(256, 2) void conv_att_kernel(
    const float* __restrict__ x, const float* __restrict__ thumb,
    const float* __restrict__ feat, float* __restrict__ out)
{
    __shared__ float buf[BUFSZ];

    int id = blockIdx.x;
    const float* src; float* dst; int H, W, b, trow, tcol;
    if (id < 1024) {                 // big: 8 batches x (16 row x 8 col) tiles
        b = id >> 7; const int t = id & 127;
        H = 512; W = 512; trow = (t >> 3) * 32; tcol = (t & 7) * 64;
        src = x; dst = out;
    } else {                         // thumb: 8 batches x 2 row tiles
        const int i2 = id - 1024;
        b = i2 >> 1; trow = (i2 & 1) * 32; tcol = 0;
        H = 64; W = 64; src = thumb;
        dst = out + (size_t)8 * 3 * 512 * 512;
    }
    const float* fb = feat + b * 360;    // uniform -> scalar loads
    const int tid = threadIdx.x;

    // ---- stage0 load: 2052 float4 slots (3ch x 38 rows x 18 quads) ----
    const float* sbg = src + (size_t)b * 3 * H * W;
    for (int q = tid; q < 2052; q += 256) {
        const int c = q / 684;                 // 684 = 38*18
        const int rem = q - c * 684;
        const int mr = rem / 18;
        const int mq = rem - mr * 18;
        const int gr = trow + mr - 3;
        const int gc0 = tcol + 4 * mq - 4;
        const bool rok = (unsigned)gr < (unsigned)H;
        const float* gp = sbg + (size_t)c * H * W + (size_t)(rok ? gr : 0) * W;
        float4 v;
        if (rok && (unsigned)gc0 <= (unsigned)(W - 4)) {
            v = *(const float4*)&gp[gc0];      // interior fast path
        } else {
            v.x = (rok && (unsigned)(gc0 + 0) < (unsigned)W) ? gp[gc0 + 0] : 0.f;
            v.y = (rok && (unsigned)(gc0 + 1) < (unsigned)W) ? gp[gc0 + 1] : 0.f;
            v.z = (rok && (unsigned)(gc0 + 2) < (unsigned)W) ? gp[gc0 + 2] : 0.f;
            v.w = (rok && (unsigned)(gc0 + 3) < (unsigned)W) ? gp[gc0 + 3] : 0.f;
        }
        *(float4*)&buf[c * CHS + mr * STRD + 4 * mq] = v;
    }
    __syncthreads();

    // conv3/output mapping (also used for residual): 16 strips x 16 groups
    const int s3 = tid >> 4;
    const int gx3 = 4 * (tid & 15);

    // conv1: 12 strips (R=3) x 18 groups = 216 units; rows -2..33, cols -4..67
    const bool act12 = tid < 216;
    const int s12 = tid / 18;
    const int g12 = tid - s12 * 18;
    const int gx12 = 4 * g12 - 4;
    float4 acc[3][3];
    if (act12) conv_rows<3, false>(buf, fb, 3 * s12 - 2, gx12, acc);

    // ---- residual stash (stage0 center, read before overwrite) ----
    float4 res[2][3];
#pragma unroll
    for (int j = 0; j < 2; ++j)
#pragma unroll
        for (int c = 0; c < 3; ++c)
            res[j][c] = *(const float4*)&buf[c * CHS + (2 * s3 + j + 3) * STRD + gx3 + 4];
    __syncthreads();

    if (act12) {
        const int r0 = 3 * s12 - 2;
#pragma unroll
        for (int j = 0; j < 3; ++j)
#pragma unroll
            for (int oc = 0; oc < 3; ++oc) {
                float4 v = acc[j][oc];
                v.x = LEAKY(v.x); v.y = LEAKY(v.y); v.z = LEAKY(v.z); v.w = LEAKY(v.w);
                *(float4*)&buf[oc * CHS + (r0 + j + 3) * STRD + gx12 + 4] = v;
            }
    }
    __syncthreads();

    // ---- conv2: rows -1..32 (strips r0=3s-1, bottom rows clipped) ----
    if (act12) conv_rows<3, true>(buf, fb + 84, 3 * s12 - 1, gx12, acc);
    __syncthreads();

    if (act12) {
        const int r0 = 3 * s12 - 1;
#pragma unroll
        for (int j = 0; j < 3; ++j) {
            if (r0 + j > 32) continue;
#pragma unroll
            for (int oc = 0; oc < 3; ++oc) {
                float4 v = acc[j][oc];
                v.x = LEAKY(v.x); v.y = LEAKY(v.y); v.z = LEAKY(v.z); v.w = LEAKY(v.w);
                *(float4*)&buf[oc * CHS + (r0 + j + 3) * STRD + gx12 + 4] = v;
            }
        }
    }
    __syncthreads();

    // ---- conv3: rows 0..31, 16 strips (R=2) x 16 groups = 256 units ----
    float4 y[2][3];
    conv_rows<2, false>(buf, fb + 168, 2 * s3, gx3, y);
#pragma unroll
    for (int j = 0; j < 2; ++j)
#pragma unroll
        for (int oc = 0; oc < 3; ++oc) {
            y[j][oc].x = LEAKY(y[j][oc].x); y[j][oc].y = LEAKY(y[j][oc].y);
            y[j][oc].z = LEAKY(y[j][oc].z); y[j][oc].w = LEAKY(y[j][oc].w);
        }

    // ---- 5x conv1x1 chain in registers ----
#pragma unroll
    for (int lay = 0; lay < 5; ++lay) {
        const float* fw = fb + 252 + lay * 12;
        const float w00 = fw[0], w01 = fw[1], w02 = fw[2];
        const float w10 = fw[3], w11 = fw[4], w12 = fw[5];
        const float w20 = fw[6], w21 = fw[7], w22 = fw[8];
        const float c0 = fw[9], c1 = fw[10], c2 = fw[11];
#pragma unroll
        for (int j = 0; j < 2; ++j) {
            float4 z0, z1, z2;
            z0.x = fmaf(y[j][0].x, w00, fmaf(y[j][1].x, w01, fmaf(y[j][2].x, w02, c0)));
            z0.y = fmaf(y[j][0].y, w00, fmaf(y[j][1].y, w01, fmaf(y[j][2].y, w02, c0)));
            z0.z = fmaf(y[j][0].z, w00, fmaf(y[j][1].z, w01, fmaf(y[j][2].z, w02, c0)));
            z0.w = fmaf(y[j][0].w, w00, fmaf(y[j][1].w, w01, fmaf(y[j][2].w, w02, c0)));
            z1.x = fmaf(y[j][0].x, w10, fmaf(y[j][1].x, w11, fmaf(y[j][2].x, w12, c1)));
            z1.y = fmaf(y[j][0].y, w10, fmaf(y[j][1].y, w11, fmaf(y[j][2].y, w12, c1)));
            z1.z = fmaf(y[j][0].z, w10, fmaf(y[j][1].z, w11, fmaf(y[j][2].z, w12, c1)));
            z1.w = fmaf(y[j][0].w, w10, fmaf(y[j][1].w, w11, fmaf(y[j][2].w, w12, c1)));
            z2.x = fmaf(y[j][0].x, w20, fmaf(y[j][1].x, w21, fmaf(y[j][2].x, w22, c2)));
            z2.y = fmaf(y[j][0].y, w20, fmaf(y[j][1].y, w21, fmaf(y[j][2].y, w22, c2)));
            z2.z = fmaf(y[j][0].z, w20, fmaf(y[j][1].z, w21, fmaf(y[j][2].z, w22, c2)));
            z2.w = fmaf(y[j][0].w, w20, fmaf(y[j][1].w, w21, fmaf(y[j][2].w, w22, c2)));
            y[j][0].x = LEAKY(z0.x); y[j][0].y = LEAKY(z0.y); y[j][0].z = LEAKY(z0.z); y[j][0].w = LEAKY(z0.w);
            y[j][1].x = LEAKY(z1.x); y[j][1].y = LEAKY(z1.y); y[j][1].z = LEAKY(z1.z); y[j][1].w = LEAKY(z1.w);
            y[j][2].x = LEAKY(z2.x); y[j][2].y = LEAKY(z2.y); y[j][2].z = LEAKY(z2.z); y[j][2].w = LEAKY(z2.w);
        }
    }

    // ---- residual + attention + float4 store ----
    const float invH = 1.f / (float)H;
    const float invW = 1.f / (float)W;
    const float wbase = (float)(tcol + gx3) * invW;
    const float4 wv = make_float4(wbase, wbase + invW, wbase + 2.f * invW, wbase + 3.f * invW);
#pragma unroll
    for (int ch = 0; ch < 3; ++ch) {
        const float* fp = fb + 312 + ch * 16;
        const float pa0 = fp[0], pb0 = fp[1], pc0 = fp[2], pd0 = fp[3];
        const float pa1 = fp[4], pb1 = fp[5], pc1 = fp[6], pd1 = fp[7];
        const float pa2 = fp[8], pb2 = fp[9], pc2 = fp[10], pd2 = fp[11];
        const float pa3 = fp[12], pb3 = fp[13], pc3 = fp[14], pd3 = fp[15];
#pragma unroll
        for (int j = 0; j < 2; ++j) {
            const int gr = trow + 2 * s3 + j;
            const float h = (float)gr * invH;
            float4 v;
            v.x = y[j][ch].x + res[j][ch].x;
            v.y = y[j][ch].y + res[j][ch].y;
            v.z = y[j][ch].z + res[j][ch].z;
            v.w = y[j][ch].w + res[j][ch].w;
            const float t0 = fmaf(pa0, h, pd0), t1 = fmaf(pa1, h, pd1);
            const float t2 = fmaf(pa2, h, pd2), t3 = fmaf(pa3, h, pd3);
            float4 o;
            {
                float a0 = fmaf(pb0, wv.x, fmaf(pc0, v.x, t0));
                a0 *= fmaf(pb1, wv.x, fmaf(pc1, v.x, t1));
                a0 *= fmaf(pb2, wv.x, fmaf(pc2, v.x, t2));
                a0 *= fmaf(pb3, wv.x, fmaf(pc3, v.x, t3));
                o.x = v.x * (1.f + a0);
                float a1 = fmaf(pb0, wv.y, fmaf(pc0, v.y, t0));
                a1 *= fmaf(pb1, wv.y, fmaf(pc1, v.y, t1));
                a1 *= fmaf(pb2, wv.y, fmaf(pc2, v.y, t2));
                a1 *= fmaf(pb3, wv.y, fmaf(pc3, v.y, t3));
                o.y = v.y * (1.f + a1);
                float a2 = fmaf(pb0, wv.z, fmaf(pc0, v.z, t0));
                a2 *= fmaf(pb1, wv.z, fmaf(pc1, v.z, t1));
                a2 *= fmaf(pb2, wv.z, fmaf(pc2, v.z, t2));
                a2 *= fmaf(pb3, wv.z, fmaf(pc3, v.z, t3));
                o.z = v.z * (1.f + a2);
                float a3 = fmaf(pb0, wv.w, fmaf(pc0, v.w, t0));
                a3 *= fmaf(pb1, wv.w, fmaf(pc1, v.w, t1));
                a3 *= fmaf(pb2, wv.w, fmaf(pc2, v.w, t2));
                a3 *= fmaf(pb3, wv.w, fmaf(pc3, v.w, t3));
                o.w = v.w * (1.f + a3);
            }
            *(float4*)&dst[((size_t)(b * 3 + ch) * H + gr) * W + tcol + gx3] = o;
        }
    }
}

extern "C" void kernel_launch(void* const* d_in, const int* in_sizes, int n_in,
                              void* d_out, int out_size, void* d_ws, size_t ws_size,
                              hipStream_t stream) {
    const float* x = (const float*)d_in[0];       // (8,3,512,512)
    const float* thumb = (const float*)d_in[1];   // (8,3,64,64)
    const float* Wm = (const float*)d_in[2];      // (3,360)
    const float* bm = (const float*)d_in[3];      // (360,)
    float* out = (float*)d_out;
    float* means = (float*)d_ws;                  // 24 floats
    float* feat = (float*)d_ws + 64;              // (8,360)

    means_kernel<<<24, 256, 0, stream>>>(thumb, means);
    fmm_kernel<<<8, 384, 0, stream>>>(Wm, bm, means, feat);
    conv_att_kernel<<<1040, 256, 0, stream>>>(x, thumb, feat, out);
}

// Round 5
// 120.425 us; speedup vs baseline: 1.4009x; 1.0362x over previous
//
#include <hip/hip_runtime.h>

// ---------------------------------------------------------------------------
// Per-batch dynamic conv stack + polynomial attention (f32).
//   feature (8,360) = mean(thumb,(2,3)) @ Wm + bm
//   conv_stack: residual + [3x conv3x3(SAME,leaky 0.2)] -> [5x conv1x1(leaky)]
//   attention:  out = y * (1 + prod_i(a*h + b*w + c*y + d)) per channel
// Outputs: x_out (8,3,512,512) then thumb_out (8,3,64,64), flat f32.
//
// R5: occupancy push. Tile 16 rows x 64 cols -> LDS 19.1KB (was 33.3KB),
// 2080 blocks (~6-8 resident/CU vs ~4) so barrier phases of different blocks
// overlap. Mappings: conv1 R=2 (180 thr), conv2 R=2 (162 thr, exact geometry,
// no clamping), conv3 R=1 (all 256 thr through the VALU-heavy tail).
// Weights via uniform s_loads; float4 LDS ops; (256,2) bounds (no spills).
// ---------------------------------------------------------------------------

#define LEAKY(v) fmaxf((v), 0.2f * (v))

constexpr int STRD = 72;            // dwords per buffered row (cols -4..67)
constexpr int ROWS0 = 22;           // rows -3..18
constexpr int CHS  = ROWS0 * STRD;  // 1584 dwords per channel slab
constexpr int BUFSZ = 3 * CHS + 16; // + pad for right-edge overread

// one kernel: per-batch channel means + (8,360) feature matmul
__global__ __launch_bounds__(256) void feat_kernel(
    const float* __restrict__ thumb, const float* __restrict__ Wm,
    const float* __restrict__ bm, float* __restrict__ feat)
{
    const int b = blockIdx.x;                // 8 blocks
    const int tid = threadIdx.x;
    __shared__ float red[256];
    __shared__ float smean[3];

    for (int c = 0; c < 3; ++c) {
        const float4* p = (const float4*)(thumb + (size_t)(b * 3 + c) * 4096);
        float s = 0.f;
#pragma unroll
        for (int k = 0; k < 4; ++k) {
            float4 v = p[tid + k * 256];
            s += v.x + v.y + v.z + v.w;
        }
        red[tid] = s;
        __syncthreads();
        for (int off = 128; off > 0; off >>= 1) {
            if (tid < off) red[tid] += red[tid + off];
            __syncthreads();
        }
        if (tid == 0) smean[c] = red[0] * (1.f / 4096.f);
        __syncthreads();
    }
    const float m0 = smean[0], m1 = smean[1], m2 = smean[2];
    for (int f = tid; f < 360; f += 256)
        feat[b * 360 + f] =
            fmaf(m0, Wm[f], fmaf(m1, Wm[360 + f], fmaf(m2, Wm[720 + f], bm[f])));
}

// 3x3 conv over a strip of R output rows x 4 cols (gx..gx+3), all 3 och.
// fw: 84 uniform weights; r0: first output row; gx: first col (multiple of 4,
// may be -4: left-edge A-clamp feeds only discarded outputs).
template<int R>
__device__ __forceinline__ void conv_rows(
    const float* __restrict__ buf, const float* __restrict__ fw,
    int r0, int gx, float4 acc[][3])
{
    const float b0 = fw[81], b1 = fw[82], b2 = fw[83];
#pragma unroll
    for (int j = 0; j < R; ++j) {
        acc[j][0] = make_float4(b0, b0, b0, b0);
        acc[j][1] = make_float4(b1, b1, b1, b1);
        acc[j][2] = make_float4(b2, b2, b2, b2);
    }
    const int gA = (gx < 0) ? 0 : gx;
#pragma unroll
    for (int ich = 0; ich < 3; ++ich) {
#pragma unroll
        for (int ri = 0; ri < R + 2; ++ri) {
            const int mr = r0 + 2 + ri;                 // = (r0-1+ri)+3
            const int idx = ich * CHS + mr * STRD;
            const float4 A = *(const float4*)&buf[idx + gA];     // gx-4..gx-1
            const float4 B = *(const float4*)&buf[idx + gx + 4]; // gx..gx+3
            const float4 C = *(const float4*)&buf[idx + gx + 8]; // gx+4..gx+7
#pragma unroll
            for (int j = 0; j < R; ++j) {
                const int dy = ri - j;
                if (dy < 0 || dy > 2) continue;
#pragma unroll
                for (int oc = 0; oc < 3; ++oc) {
                    const float w0 = fw[oc * 27 + ich * 9 + dy * 3 + 0];
                    const float w1 = fw[oc * 27 + ich * 9 + dy * 3 + 1];
                    const float w2 = fw[oc * 27 + ich * 9 + dy * 3 + 2];
                    float4& a = acc[j][oc];
                    a.x = fmaf(A.w, w0, fmaf(B.x, w1, fmaf(B.y, w2, a.x)));
                    a.y = fmaf(B.x, w0, fmaf(B.y, w1, fmaf(B.z, w2, a.y)));
                    a.z = fmaf(B.y, w0, fmaf(B.z, w1, fmaf(B.w, w2, a.z)));
                    a.w = fmaf(B.z, w0, fmaf(B.w, w1, fmaf(C.x, w2, a.w)));
                }
            }
        }
    }
}

__global__ __launch_bounds__(256, 2) void conv_att_kernel(
    const float* __restrict__ x, const float* __restrict__ thumb,
    const float* __restrict__ feat, float* __restrict__ out)
{
    __shared__ float buf[BUFSZ];

    int id = blockIdx.x;
    const float* src; float* dst; int H, W, b, trow, tcol;
    if (id < 2048) {                 // big: 8 batches x (32 row x 8 col) tiles
        b = id >> 8; const int t = id & 255;
        H = 512; W = 512; trow = (t >> 3) * 16; tcol = (t & 7) * 64;
        src = x; dst = out;
    } else {                         // thumb: 8 batches x 4 row tiles
        const int i2 = id - 2048;
        b = i2 >> 2; trow = (i2 & 3) * 16; tcol = 0;
        H = 64; W = 64; src = thumb;
        dst = out + (size_t)8 * 3 * 512 * 512;
    }
    const float* fb = feat + b * 360;    // uniform -> scalar loads
    const int tid = threadIdx.x;

    // ---- stage0 load: 1188 float4 slots (3ch x 22 rows x 18 quads) ----
    const float* sbg = src + (size_t)b * 3 * H * W;
    for (int q = tid; q < 1188; q += 256) {
        const int c = q / 396;                 // 396 = 22*18
        const int rem = q - c * 396;
        const int mr = rem / 18;
        const int mq = rem - mr * 18;
        const int gr = trow + mr - 3;
        const int gc0 = tcol + 4 * mq - 4;
        const bool rok = (unsigned)gr < (unsigned)H;
        const float* gp = sbg + (size_t)c * H * W + (size_t)(rok ? gr : 0) * W;
        float4 v;
        if (rok && (unsigned)gc0 <= (unsigned)(W - 4)) {
            v = *(const float4*)&gp[gc0];      // interior fast path
        } else {
            v.x = (rok && (unsigned)(gc0 + 0) < (unsigned)W) ? gp[gc0 + 0] : 0.f;
            v.y = (rok && (unsigned)(gc0 + 1) < (unsigned)W) ? gp[gc0 + 1] : 0.f;
            v.z = (rok && (unsigned)(gc0 + 2) < (unsigned)W) ? gp[gc0 + 2] : 0.f;
            v.w = (rok && (unsigned)(gc0 + 3) < (unsigned)W) ? gp[gc0 + 3] : 0.f;
        }
        *(float4*)&buf[c * CHS + mr * STRD + 4 * mq] = v;
    }
    __syncthreads();

    // conv3/output mapping (also residual): 16 rows x 16 quad-groups, R=1
    const int s3 = tid >> 4;             // output row 0..15
    const int gx3 = 4 * (tid & 15);      // output col group

    // conv1: 10 strips (R=2, rows -2..17) x 18 groups = 180 units
    const bool act1 = tid < 180;
    const int s1 = tid / 18;
    const int gx1 = 4 * (tid - s1 * 18) - 4;
    float4 acc[2][3];
    if (act1) conv_rows<2>(buf, fb, 2 * s1 - 2, gx1, acc);

    // residual stash (stage0 center, read before overwrite)
    float4 res[3];
#pragma unroll
    for (int c = 0; c < 3; ++c)
        res[c] = *(const float4*)&buf[c * CHS + (s3 + 3) * STRD + gx3 + 4];
    __syncthreads();

    if (act1) {
        const int r0 = 2 * s1 - 2;
#pragma unroll
        for (int j = 0; j < 2; ++j)
#pragma unroll
            for (int oc = 0; oc < 3; ++oc) {
                float4 v = acc[j][oc];
                v.x = LEAKY(v.x); v.y = LEAKY(v.y); v.z = LEAKY(v.z); v.w = LEAKY(v.w);
                *(float4*)&buf[oc * CHS + (r0 + j + 3) * STRD + gx1 + 4] = v;
            }
    }
    __syncthreads();

    // conv2: 9 strips (R=2, rows -1..16) x 18 groups = 162 units (exact)
    const bool act2 = tid < 162;
    const int s2 = tid / 18;
    const int gx2 = 4 * (tid - s2 * 18) - 4;
    if (act2) conv_rows<2>(buf, fb + 84, 2 * s2 - 1, gx2, acc);
    __syncthreads();

    if (act2) {
        const int r0 = 2 * s2 - 1;
#pragma unroll
        for (int j = 0; j < 2; ++j)
#pragma unroll
            for (int oc = 0; oc < 3; ++oc) {
                float4 v = acc[j][oc];
                v.x = LEAKY(v.x); v.y = LEAKY(v.y); v.z = LEAKY(v.z); v.w = LEAKY(v.w);
                *(float4*)&buf[oc * CHS + (r0 + j + 3) * STRD + gx2 + 4] = v;
            }
    }
    __syncthreads();

    // conv3: rows 0..15, R=1, all 256 threads
    float4 y[1][3];
    conv_rows<1>(buf, fb + 168, s3, gx3, y);
    float4 y0 = y[0][0], y1 = y[0][1], y2 = y[0][2];
    y0.x = LEAKY(y0.x); y0.y = LEAKY(y0.y); y0.z = LEAKY(y0.z); y0.w = LEAKY(y0.w);
    y1.x = LEAKY(y1.x); y1.y = LEAKY(y1.y); y1.z = LEAKY(y1.z); y1.w = LEAKY(y1.w);
    y2.x = LEAKY(y2.x); y2.y = LEAKY(y2.y); y2.z = LEAKY(y2.z); y2.w = LEAKY(y2.w);

    // ---- 5x conv1x1 chain in registers ----
#pragma unroll
    for (int lay = 0; lay < 5; ++lay) {
        const float* fw = fb + 252 + lay * 12;
        const float w00 = fw[0], w01 = fw[1], w02 = fw[2];
        const float w10 = fw[3], w11 = fw[4], w12 = fw[5];
        const float w20 = fw[6], w21 = fw[7], w22 = fw[8];
        const float c0 = fw[9], c1 = fw[10], c2 = fw[11];
        float4 z0, z1, z2;
        z0.x = fmaf(y0.x, w00, fmaf(y1.x, w01, fmaf(y2.x, w02, c0)));
        z0.y = fmaf(y0.y, w00, fmaf(y1.y, w01, fmaf(y2.y, w02, c0)));
        z0.z = fmaf(y0.z, w00, fmaf(y1.z, w01, fmaf(y2.z, w02, c0)));
        z0.w = fmaf(y0.w, w00, fmaf(y1.w, w01, fmaf(y2.w, w02, c0)));
        z1.x = fmaf(y0.x, w10, fmaf(y1.x, w11, fmaf(y2.x, w12, c1)));
        z1.y = fmaf(y0.y, w10, fmaf(y1.y, w11, fmaf(y2.y, w12, c1)));
        z1.z = fmaf(y0.z, w10, fmaf(y1.z, w11, fmaf(y2.z, w12, c1)));
        z1.w = fmaf(y0.w, w10, fmaf(y1.w, w11, fmaf(y2.w, w12, c1)));
        z2.x = fmaf(y0.x, w20, fmaf(y1.x, w21, fmaf(y2.x, w22, c2)));
        z2.y = fmaf(y0.y, w20, fmaf(y1.y, w21, fmaf(y2.y, w22, c2)));
        z2.z = fmaf(y0.z, w20, fmaf(y1.z, w21, fmaf(y2.z, w22, c2)));
        z2.w = fmaf(y0.w, w20, fmaf(y1.w, w21, fmaf(y2.w, w22, c2)));
        y0.x = LEAKY(z0.x); y0.y = LEAKY(z0.y); y0.z = LEAKY(z0.z); y0.w = LEAKY(z0.w);
        y1.x = LEAKY(z1.x); y1.y = LEAKY(z1.y); y1.z = LEAKY(z1.z); y1.w = LEAKY(z1.w);
        y2.x = LEAKY(z2.x); y2.y = LEAKY(z2.y); y2.z = LEAKY(z2.z); y2.w = LEAKY(z2.w);
    }

    // ---- residual + attention + float4 store (1 row x 4 cols x 3 ch) ----
    const float invH = 1.f / (float)H;
    const float invW = 1.f / (float)W;
    const int gr = trow + s3;
    const float h = (float)gr * invH;
    const float wbase = (float)(tcol + gx3) * invW;
    const float4 wv = make_float4(wbase, wbase + invW, wbase + 2.f * invW, wbase + 3.f * invW);
#pragma unroll
    for (int ch = 0; ch < 3; ++ch) {
        const float* fp = fb + 312 + ch * 16;
        const float pa0 = fp[0], pb0 = fp[1], pc0 = fp[2], pd0 = fp[3];
        const float pa1 = fp[4], pb1 = fp[5], pc1 = fp[6], pd1 = fp[7];
        const float pa2 = fp[8], pb2 = fp[9], pc2 = fp[10], pd2 = fp[11];
        const float pa3 = fp[12], pb3 = fp[13], pc3 = fp[14], pd3 = fp[15];
        const float4 yv = (ch == 0) ? y0 : (ch == 1) ? y1 : y2;
        float4 v;
        v.x = yv.x + res[ch].x;
        v.y = yv.y + res[ch].y;
        v.z = yv.z + res[ch].z;
        v.w = yv.w + res[ch].w;
        const float t0 = fmaf(pa0, h, pd0), t1 = fmaf(pa1, h, pd1);
        const float t2 = fmaf(pa2, h, pd2), t3 = fmaf(pa3, h, pd3);
        float4 o;
        float a0 = fmaf(pb0, wv.x, fmaf(pc0, v.x, t0));
        a0 *= fmaf(pb1, wv.x, fmaf(pc1, v.x, t1));
        a0 *= fmaf(pb2, wv.x, fmaf(pc2, v.x, t2));
        a0 *= fmaf(pb3, wv.x, fmaf(pc3, v.x, t3));
        o.x = v.x * (1.f + a0);
        float a1 = fmaf(pb0, wv.y, fmaf(pc0, v.y, t0));
        a1 *= fmaf(pb1, wv.y, fmaf(pc1, v.y, t1));
        a1 *= fmaf(pb2, wv.y, fmaf(pc2, v.y, t2));
        a1 *= fmaf(pb3, wv.y, fmaf(pc3, v.y, t3));
        o.y = v.y * (1.f + a1);
        float a2 = fmaf(pb0, wv.z, fmaf(pc0, v.z, t0));
        a2 *= fmaf(pb1, wv.z, fmaf(pc1, v.z, t1));
        a2 *= fmaf(pb2, wv.z, fmaf(pc2, v.z, t2));
        a2 *= fmaf(pb3, wv.z, fmaf(pc3, v.z, t3));
        o.z = v.z * (1.f + a2);
        float a3 = fmaf(pb0, wv.w, fmaf(pc0, v.w, t0));
        a3 *= fmaf(pb1, wv.w, fmaf(pc1, v.w, t1));
        a3 *= fmaf(pb2, wv.w, fmaf(pc2, v.w, t2));
        a3 *= fmaf(pb3, wv.w, fmaf(pc3, v.w, t3));
        o.w = v.w * (1.f + a3);
        *(float4*)&dst[((size_t)(b * 3 + ch) * H + gr) * W + tcol + gx3] = o;
    }
}

extern "C" void kernel_launch(void* const* d_in, const int* in_sizes, int n_in,
                              void* d_out, int out_size, void* d_ws, size_t ws_size,
                              hipStream_t stream) {
    const float* x = (const float*)d_in[0];       // (8,3,512,512)
    const float* thumb = (const float*)d_in[1];   // (8,3,64,64)
    const float* Wm = (const float*)d_in[2];      // (3,360)
    const float* bm = (const float*)d_in[3];      // (360,)
    float* out = (float*)d_out;
    float* feat = (float*)d_ws;                   // (8,360)

    feat_kernel<<<8, 256, 0, stream>>>(thumb, Wm, bm, feat);
    // 2048 big-image blocks + 32 thumb blocks
    conv_att_kernel<<<2080, 256, 0, stream>>>(x, thumb, feat, out);
}